// Round 8
// baseline (543.743 us; speedup 1.0000x reference)
//
#include <hip/hip_runtime.h>
#include <hip/hip_bf16.h>
#include <cmath>

// Problem: N=64, T=512, D=256, H=256 (all fp32)
//   c   = x @ Wx + b          (N,T,H)  -- parallel GEMM
//   h_t = tanh(c_t + h_{t-1} @ Wh)     -- sequential scan
// Output: all h_t, (N,T,H).
//
// Round-8 = Round-7 resubmitted (R7 bench died at container level, no
// kernel diagnostic; topology identical to the R6 run that passed).
//
// Scan: PACK W AS FP16 PAIRS -> 64 W values in 32 VGPRs. Total live set
// ~62 regs fits the allocator's preferred 64-reg tier, so there is no
// spill incentive left (fp32 W needed ~100 regs -> spilled in R0-R5).
// FMAs via v_fma_mix_f32: f32 h * f16 W (op_sel lo/hi) + f32 acc, one
// instruction per FMA, full-precision h and accumulation.
//  - W traffic/step: 256 KB -> 0. Step floor ~512 cy FMA + ~250 reduction.
//  - fusion (R6) kept: gemm blocks produce c chunks, scan blocks gated
//    by agent-scope flags in d_ws.
//  - waves_per_eu(4,4): if honored, scan block fills its CU's VGPR file
//    -> exclusive CU tenancy during the GEMM ramp.

#define KDIM  256
#define HDIM  256
#define TSTEPS 512
#define NBATCH 64
#define SCAN_BLOCKS 64
#define CH_STEPS 64            // t-steps per chunk
#define NCH 8                  // chunks per row
#define GEMM_BLOCKS (NCH * NBATCH)   // 512
#define SMEM_BYTES 41984       // max(scan 17408, gemm 8704+33280)

__device__ __forceinline__ unsigned pack2(float lo, float hi) {
    _Float16 fa = (_Float16)lo, fb = (_Float16)hi;   // RTE converts
    unsigned short a, b;
    __builtin_memcpy(&a, &fa, 2);
    __builtin_memcpy(&b, &fb, 2);
    return (unsigned)a | ((unsigned)b << 16);
}

// 16 v_fma_mix_f32: ACC += h_{2k} * lo(P_k) + h_{2k+1} * hi(P_k), k=0..7.
// %0 = ACC (f32), %1-%16 = h0..h15 (f32), %17-%24 = P0..P7 (packed f16x2).
#define FMAMIX16(ACC, P0,P1,P2,P3,P4,P5,P6,P7)                                 \
    asm("v_fma_mix_f32 %0, %1, %17, %0 op_sel:[0,0,0] op_sel_hi:[0,1,0]\n\t"   \
        "v_fma_mix_f32 %0, %2, %17, %0 op_sel:[0,1,0] op_sel_hi:[0,1,0]\n\t"   \
        "v_fma_mix_f32 %0, %3, %18, %0 op_sel:[0,0,0] op_sel_hi:[0,1,0]\n\t"   \
        "v_fma_mix_f32 %0, %4, %18, %0 op_sel:[0,1,0] op_sel_hi:[0,1,0]\n\t"   \
        "v_fma_mix_f32 %0, %5, %19, %0 op_sel:[0,0,0] op_sel_hi:[0,1,0]\n\t"   \
        "v_fma_mix_f32 %0, %6, %19, %0 op_sel:[0,1,0] op_sel_hi:[0,1,0]\n\t"   \
        "v_fma_mix_f32 %0, %7, %20, %0 op_sel:[0,0,0] op_sel_hi:[0,1,0]\n\t"   \
        "v_fma_mix_f32 %0, %8, %20, %0 op_sel:[0,1,0] op_sel_hi:[0,1,0]\n\t"   \
        "v_fma_mix_f32 %0, %9, %21, %0 op_sel:[0,0,0] op_sel_hi:[0,1,0]\n\t"   \
        "v_fma_mix_f32 %0, %10, %21, %0 op_sel:[0,1,0] op_sel_hi:[0,1,0]\n\t"  \
        "v_fma_mix_f32 %0, %11, %22, %0 op_sel:[0,0,0] op_sel_hi:[0,1,0]\n\t"  \
        "v_fma_mix_f32 %0, %12, %22, %0 op_sel:[0,1,0] op_sel_hi:[0,1,0]\n\t"  \
        "v_fma_mix_f32 %0, %13, %23, %0 op_sel:[0,0,0] op_sel_hi:[0,1,0]\n\t"  \
        "v_fma_mix_f32 %0, %14, %23, %0 op_sel:[0,1,0] op_sel_hi:[0,1,0]\n\t"  \
        "v_fma_mix_f32 %0, %15, %24, %0 op_sel:[0,0,0] op_sel_hi:[0,1,0]\n\t"  \
        "v_fma_mix_f32 %0, %16, %24, %0 op_sel:[0,1,0] op_sel_hi:[0,1,0]\n\t"  \
        : "+v"(ACC)                                                            \
        : "v"(h0), "v"(h1), "v"(h2), "v"(h3),                                  \
          "v"(h4), "v"(h5), "v"(h6), "v"(h7),                                  \
          "v"(h8), "v"(h9), "v"(h10), "v"(h11),                                \
          "v"(h12), "v"(h13), "v"(h14), "v"(h15),                              \
          "v"(P0), "v"(P1), "v"(P2), "v"(P3),                                  \
          "v"(P4), "v"(P5), "v"(P6), "v"(P7))

// Load W rows 2K,2K+1 and pack per-column fp16 pairs (k-pair packed in one reg).
#define LDW2(K)                                                                \
    float4 ta##K = *(const float4*)(wp + (2*(K)) * HDIM);                      \
    float4 tb##K = *(const float4*)(wp + (2*(K)+1) * HDIM);                    \
    unsigned wA##K = pack2(ta##K.x, tb##K.x);                                  \
    unsigned wB##K = pack2(ta##K.y, tb##K.y);                                  \
    unsigned wC##K = pack2(ta##K.z, tb##K.z);                                  \
    unsigned wD##K = pack2(ta##K.w, tb##K.w);

#define PIN8(P)                                                                \
    asm volatile("" : "+v"(P##0), "+v"(P##1), "+v"(P##2), "+v"(P##3),          \
                      "+v"(P##4), "+v"(P##5), "+v"(P##6), "+v"(P##7))

// mode: 0 = fused (flags valid), 1 = gemm-only (no signal), 2 = scan-only (no wait)
__global__ __launch_bounds__(1024)
__attribute__((amdgpu_waves_per_eu(4, 4)))
void fused(
    const float* __restrict__ x,    // (32768, 256)
    const float* __restrict__ h0v,  // (64, 256)
    const float* __restrict__ Wx,   // (256, 256)
    const float* __restrict__ Wh,   // (256, 256)
    const float* __restrict__ bias, // (256)
    float* __restrict__ out,        // (64, 512, 256): c, overwritten by h
    unsigned int* flags,            // (64, 8) in d_ws
    int mode)
{
    __shared__ __align__(16) char smem[SMEM_BYTES];
    const int tid = threadIdx.x;

    if (mode == 1 && blockIdx.x < SCAN_BLOCKS) return;   // gemm-only pass
    const bool is_scan = (mode == 2) || (mode == 0 && blockIdx.x < SCAN_BLOCKS);

    if (!is_scan) {
        // ======================= GEMM: 64m x 256n tile =======================
        float (*As)[68]  = (float(*)[68])smem;            // [k][m] transposed
        float (*Bs)[260] = (float(*)[260])(smem + 8704);  // [k][n]

        const int bm = (int)blockIdx.x - SCAN_BLOCKS;     // 0..511
        const int r  = bm & 63;
        const int ch = bm >> 6;                           // ch-major dispatch
        const int m0 = r * TSTEPS + ch * CH_STEPS;
        const int tx = tid & 63;                          // 4 cols each
        const int ty = tid >> 6;                          // 0..15, 4 rows each

        float acc[4][4];
#pragma unroll
        for (int i = 0; i < 4; ++i)
#pragma unroll
            for (int j = 0; j < 4; ++j) acc[i][j] = 0.f;

        for (int kc = 0; kc < KDIM; kc += 32) {
            if (tid < 512) {                              // stage A transposed
                int arow = tid >> 3;                      // 0..63 (m)
                int ac4  = (tid & 7) << 2;                // 0..28 (k)
                float4 va = *(const float4*)&x[(size_t)(m0 + arow) * KDIM + kc + ac4];
                As[ac4 + 0][arow] = va.x;
                As[ac4 + 1][arow] = va.y;
                As[ac4 + 2][arow] = va.z;
                As[ac4 + 3][arow] = va.w;
            }
            {                                             // stage B (2 rows/thread)
                int brow = tid >> 6;                      // 0..15 (k)
                int bc4  = (tid & 63) << 2;               // 0..252 (n)
                *(float4*)&Bs[brow][bc4] =
                    *(const float4*)&Wx[(size_t)(kc + brow) * HDIM + bc4];
                *(float4*)&Bs[brow + 16][bc4] =
                    *(const float4*)&Wx[(size_t)(kc + brow + 16) * HDIM + bc4];
            }
            __syncthreads();

#pragma unroll
            for (int kk = 0; kk < 32; ++kk) {
                float4 a = *(const float4*)&As[kk][ty * 4];  // wave-uniform (bcast)
                float4 b = *(const float4*)&Bs[kk][tx * 4];
                acc[0][0] += a.x * b.x; acc[0][1] += a.x * b.y;
                acc[0][2] += a.x * b.z; acc[0][3] += a.x * b.w;
                acc[1][0] += a.y * b.x; acc[1][1] += a.y * b.y;
                acc[1][2] += a.y * b.z; acc[1][3] += a.y * b.w;
                acc[2][0] += a.z * b.x; acc[2][1] += a.z * b.y;
                acc[2][2] += a.z * b.z; acc[2][3] += a.z * b.w;
                acc[3][0] += a.w * b.x; acc[3][1] += a.w * b.y;
                acc[3][2] += a.w * b.z; acc[3][3] += a.w * b.w;
            }
            __syncthreads();
        }

        float4 bj = *(const float4*)&bias[tx * 4];
#pragma unroll
        for (int i = 0; i < 4; ++i) {
            float4 v;
            v.x = acc[i][0] + bj.x;
            v.y = acc[i][1] + bj.y;
            v.z = acc[i][2] + bj.z;
            v.w = acc[i][3] + bj.w;
            *(float4*)&out[(size_t)(m0 + ty * 4 + i) * HDIM + tx * 4] = v;
        }

        if (mode == 0) {
            __syncthreads();    // all stores program-ordered before signal (hb)
            if (tid == 0)
                __hip_atomic_fetch_add(&flags[r * NCH + ch], 1u,
                                       __ATOMIC_RELEASE, __HIP_MEMORY_SCOPE_AGENT);
        }
        return;
    }

    // ================= SCAN: fp16-packed register-resident W =================
    float* h = (float*)smem;                          // 256 floats
    float (*red)[256] = (float(*)[256])(smem + 1024); // [16][256] partials

    const int r   = (int)blockIdx.x;
    const int jq  = tid & 63;       // column quad
    const int g   = tid >> 6;       // k-group (0..15)
    const int j0  = jq << 2;

    // W tile: cols j0..j0+3 x k in [16g,16g+16), packed as fp16 k-pairs.
    // 32 VGPRs total -> fits the 64-reg tier, no spill incentive.
    const float* wp = Wh + (size_t)(g * 16) * HDIM + j0;
    LDW2(0) LDW2(1) LDW2(2) LDW2(3) LDW2(4) LDW2(5) LDW2(6) LDW2(7)
    PIN8(wA); PIN8(wB); PIN8(wC); PIN8(wD);

    if (tid < 256) h[tid] = h0v[(size_t)r * HDIM + tid];

    float* outr = out + (size_t)r * TSTEPS * HDIM;
    __syncthreads();

    float c_next = 0.f;
    for (int ch = 0; ch < NCH; ++ch) {
        if (mode == 0) {
            if (tid == 0) {
                const unsigned int* f = &flags[r * NCH + ch];
                while (__hip_atomic_load(f, __ATOMIC_RELAXED,
                                         __HIP_MEMORY_SCOPE_AGENT) == 0u)
                    __builtin_amdgcn_s_sleep(8);
                (void)__hip_atomic_load(f, __ATOMIC_ACQUIRE,
                                        __HIP_MEMORY_SCOPE_AGENT);
            }
            __syncthreads();    // acquire happens-before everyone's c reads
        }
        if (g < 4) c_next = outr[(size_t)(ch * CH_STEPS) * HDIM + tid];

        for (int tt = 0; tt < CH_STEPS; ++tt) {
            const int t = ch * CH_STEPS + tt;
            float c = c_next;
            if (g < 4 && tt + 1 < CH_STEPS)     // stay inside gated chunk
                c_next = outr[(size_t)(t + 1) * HDIM + tid];

            const float4* hv = (const float4*)(h + (g << 4));
            float4 ha = hv[0], hb = hv[1], hc = hv[2], hd = hv[3];
            float h0 = ha.x, h1 = ha.y, h2 = ha.z, h3 = ha.w;
            float h4 = hb.x, h5 = hb.y, h6 = hb.z, h7 = hb.w;
            float h8 = hc.x, h9 = hc.y, h10 = hc.z, h11 = hc.w;
            float h12 = hd.x, h13 = hd.y, h14 = hd.z, h15 = hd.w;

            float a0 = 0.f, a1 = 0.f, a2 = 0.f, a3 = 0.f;
            FMAMIX16(a0, wA0,wA1,wA2,wA3,wA4,wA5,wA6,wA7);
            FMAMIX16(a1, wB0,wB1,wB2,wB3,wB4,wB5,wB6,wB7);
            FMAMIX16(a2, wC0,wC1,wC2,wC3,wC4,wC5,wC6,wC7);
            FMAMIX16(a3, wD0,wD1,wD2,wD3,wD4,wD5,wD6,wD7);

            float4 accv; accv.x = a0; accv.y = a1; accv.z = a2; accv.w = a3;
            *(float4*)&red[g][j0] = accv;
            __syncthreads();

            if (tid < 256) {
                float s0 = red[0][tid] + red[1][tid];
                float s1 = red[2][tid] + red[3][tid];
                float s2 = red[4][tid] + red[5][tid];
                float s3 = red[6][tid] + red[7][tid];
                float s4 = red[8][tid] + red[9][tid];
                float s5 = red[10][tid] + red[11][tid];
                float s6 = red[12][tid] + red[13][tid];
                float s7 = red[14][tid] + red[15][tid];
                float s  = (((s0 + s1) + (s2 + s3)) + ((s4 + s5) + (s6 + s7))) + c;
                float e  = __expf(2.f * s);
                float hn = 1.f - 2.f / (e + 1.f);
                outr[(size_t)t * HDIM + tid] = hn;
                h[tid] = hn;
            }
            __syncthreads();
        }
    }
}

extern "C" void kernel_launch(void* const* d_in, const int* in_sizes, int n_in,
                              void* d_out, int out_size, void* d_ws, size_t ws_size,
                              hipStream_t stream) {
    const float* x  = (const float*)d_in[0];   // (64,512,256)
    const float* h0 = (const float*)d_in[1];   // (64,256)
    const float* Wx = (const float*)d_in[2];   // (256,256)
    const float* Wh = (const float*)d_in[3];   // (256,256)
    const float* b  = (const float*)d_in[4];   // (256)
    float* out = (float*)d_out;                // (64,512,256)

    const size_t flag_bytes = (size_t)NBATCH * NCH * sizeof(unsigned int);
    if (d_ws != nullptr && ws_size >= flag_bytes) {
        unsigned int* flags = (unsigned int*)d_ws;
        hipMemsetAsync(d_ws, 0, flag_bytes, stream);
        fused<<<SCAN_BLOCKS + GEMM_BLOCKS, 1024, 0, stream>>>(
            x, h0, Wx, Wh, b, out, flags, 0);
    } else {
        // Fallback: serialized two-pass.
        fused<<<SCAN_BLOCKS + GEMM_BLOCKS, 1024, 0, stream>>>(
            x, h0, Wx, Wh, b, out, nullptr, 1);
        fused<<<SCAN_BLOCKS, 1024, 0, stream>>>(
            x, h0, Wx, Wh, b, out, nullptr, 2);
    }
}

// Round 9
// 534.281 us; speedup vs baseline: 1.0177x; 1.0177x over previous
//
#include <hip/hip_runtime.h>
#include <hip/hip_bf16.h>
#include <cmath>

// Problem: N=64, T=512, D=256, H=256 (all fp32)
//   c   = x @ Wx + b          (N,T,H)  -- parallel GEMM
//   h_t = tanh(c_t + h_{t-1} @ Wh)     -- sequential scan
// Output: all h_t, (N,T,H).
//
// Round-9 = Round-8 MINUS waves_per_eu(4,4)  (single-variable A/B).
// R8 showed conserved VALU busy-cycles but +77us idle vs R6: the
// waves_per_eu cap halved GEMM occupancy (1 block/CU), starving the
// scan's chunk-flags -> scan slept. Default budget for this shape is
// already 64 VGPR (2 blocks/CU, 8 waves/EU), and the fp16-packed W
// live set (~62) fits it -> the attribute was never needed for W
// residency; it only throttled the producer.
//
// Scan: W packed as fp16 pairs, 64 weights in 32 VGPRs, register
// resident. FMAs via v_fma_mix_f32 (f32 h x f16 W + f32 acc).
// Fusion (R6): gemm blocks produce c chunks, scan blocks gated by
// agent-scope flags in d_ws.

#define KDIM  256
#define HDIM  256
#define TSTEPS 512
#define NBATCH 64
#define SCAN_BLOCKS 64
#define CH_STEPS 64            // t-steps per chunk
#define NCH 8                  // chunks per row
#define GEMM_BLOCKS (NCH * NBATCH)   // 512
#define SMEM_BYTES 41984       // max(scan 17408, gemm 8704+33280)

__device__ __forceinline__ unsigned pack2(float lo, float hi) {
    _Float16 fa = (_Float16)lo, fb = (_Float16)hi;   // RTE converts
    unsigned short a, b;
    __builtin_memcpy(&a, &fa, 2);
    __builtin_memcpy(&b, &fb, 2);
    return (unsigned)a | ((unsigned)b << 16);
}

// 16 v_fma_mix_f32: ACC += h_{2k} * lo(P_k) + h_{2k+1} * hi(P_k), k=0..7.
// %0 = ACC (f32), %1-%16 = h0..h15 (f32), %17-%24 = P0..P7 (packed f16x2).
#define FMAMIX16(ACC, P0,P1,P2,P3,P4,P5,P6,P7)                                 \
    asm("v_fma_mix_f32 %0, %1, %17, %0 op_sel:[0,0,0] op_sel_hi:[0,1,0]\n\t"   \
        "v_fma_mix_f32 %0, %2, %17, %0 op_sel:[0,1,0] op_sel_hi:[0,1,0]\n\t"   \
        "v_fma_mix_f32 %0, %3, %18, %0 op_sel:[0,0,0] op_sel_hi:[0,1,0]\n\t"   \
        "v_fma_mix_f32 %0, %4, %18, %0 op_sel:[0,1,0] op_sel_hi:[0,1,0]\n\t"   \
        "v_fma_mix_f32 %0, %5, %19, %0 op_sel:[0,0,0] op_sel_hi:[0,1,0]\n\t"   \
        "v_fma_mix_f32 %0, %6, %19, %0 op_sel:[0,1,0] op_sel_hi:[0,1,0]\n\t"   \
        "v_fma_mix_f32 %0, %7, %20, %0 op_sel:[0,0,0] op_sel_hi:[0,1,0]\n\t"   \
        "v_fma_mix_f32 %0, %8, %20, %0 op_sel:[0,1,0] op_sel_hi:[0,1,0]\n\t"   \
        "v_fma_mix_f32 %0, %9, %21, %0 op_sel:[0,0,0] op_sel_hi:[0,1,0]\n\t"   \
        "v_fma_mix_f32 %0, %10, %21, %0 op_sel:[0,1,0] op_sel_hi:[0,1,0]\n\t"  \
        "v_fma_mix_f32 %0, %11, %22, %0 op_sel:[0,0,0] op_sel_hi:[0,1,0]\n\t"  \
        "v_fma_mix_f32 %0, %12, %22, %0 op_sel:[0,1,0] op_sel_hi:[0,1,0]\n\t"  \
        "v_fma_mix_f32 %0, %13, %23, %0 op_sel:[0,0,0] op_sel_hi:[0,1,0]\n\t"  \
        "v_fma_mix_f32 %0, %14, %23, %0 op_sel:[0,1,0] op_sel_hi:[0,1,0]\n\t"  \
        "v_fma_mix_f32 %0, %15, %24, %0 op_sel:[0,0,0] op_sel_hi:[0,1,0]\n\t"  \
        "v_fma_mix_f32 %0, %16, %24, %0 op_sel:[0,1,0] op_sel_hi:[0,1,0]\n\t"  \
        : "+v"(ACC)                                                            \
        : "v"(h0), "v"(h1), "v"(h2), "v"(h3),                                  \
          "v"(h4), "v"(h5), "v"(h6), "v"(h7),                                  \
          "v"(h8), "v"(h9), "v"(h10), "v"(h11),                                \
          "v"(h12), "v"(h13), "v"(h14), "v"(h15),                              \
          "v"(P0), "v"(P1), "v"(P2), "v"(P3),                                  \
          "v"(P4), "v"(P5), "v"(P6), "v"(P7))

// Load W rows 2K,2K+1 and pack per-column fp16 pairs (k-pair packed in one reg).
#define LDW2(K)                                                                \
    float4 ta##K = *(const float4*)(wp + (2*(K)) * HDIM);                      \
    float4 tb##K = *(const float4*)(wp + (2*(K)+1) * HDIM);                    \
    unsigned wA##K = pack2(ta##K.x, tb##K.x);                                  \
    unsigned wB##K = pack2(ta##K.y, tb##K.y);                                  \
    unsigned wC##K = pack2(ta##K.z, tb##K.z);                                  \
    unsigned wD##K = pack2(ta##K.w, tb##K.w);

#define PIN8(P)                                                                \
    asm volatile("" : "+v"(P##0), "+v"(P##1), "+v"(P##2), "+v"(P##3),          \
                      "+v"(P##4), "+v"(P##5), "+v"(P##6), "+v"(P##7))

// mode: 0 = fused (flags valid), 1 = gemm-only (no signal), 2 = scan-only (no wait)
__global__ __launch_bounds__(1024) void fused(
    const float* __restrict__ x,    // (32768, 256)
    const float* __restrict__ h0v,  // (64, 256)
    const float* __restrict__ Wx,   // (256, 256)
    const float* __restrict__ Wh,   // (256, 256)
    const float* __restrict__ bias, // (256)
    float* __restrict__ out,        // (64, 512, 256): c, overwritten by h
    unsigned int* flags,            // (64, 8) in d_ws
    int mode)
{
    __shared__ __align__(16) char smem[SMEM_BYTES];
    const int tid = threadIdx.x;

    if (mode == 1 && blockIdx.x < SCAN_BLOCKS) return;   // gemm-only pass
    const bool is_scan = (mode == 2) || (mode == 0 && blockIdx.x < SCAN_BLOCKS);

    if (!is_scan) {
        // ======================= GEMM: 64m x 256n tile =======================
        float (*As)[68]  = (float(*)[68])smem;            // [k][m] transposed
        float (*Bs)[260] = (float(*)[260])(smem + 8704);  // [k][n]

        const int bm = (int)blockIdx.x - SCAN_BLOCKS;     // 0..511
        const int r  = bm & 63;
        const int ch = bm >> 6;                           // ch-major dispatch
        const int m0 = r * TSTEPS + ch * CH_STEPS;
        const int tx = tid & 63;                          // 4 cols each
        const int ty = tid >> 6;                          // 0..15, 4 rows each

        float acc[4][4];
#pragma unroll
        for (int i = 0; i < 4; ++i)
#pragma unroll
            for (int j = 0; j < 4; ++j) acc[i][j] = 0.f;

        for (int kc = 0; kc < KDIM; kc += 32) {
            if (tid < 512) {                              // stage A transposed
                int arow = tid >> 3;                      // 0..63 (m)
                int ac4  = (tid & 7) << 2;                // 0..28 (k)
                float4 va = *(const float4*)&x[(size_t)(m0 + arow) * KDIM + kc + ac4];
                As[ac4 + 0][arow] = va.x;
                As[ac4 + 1][arow] = va.y;
                As[ac4 + 2][arow] = va.z;
                As[ac4 + 3][arow] = va.w;
            }
            {                                             // stage B (2 rows/thread)
                int brow = tid >> 6;                      // 0..15 (k)
                int bc4  = (tid & 63) << 2;               // 0..252 (n)
                *(float4*)&Bs[brow][bc4] =
                    *(const float4*)&Wx[(size_t)(kc + brow) * HDIM + bc4];
                *(float4*)&Bs[brow + 16][bc4] =
                    *(const float4*)&Wx[(size_t)(kc + brow + 16) * HDIM + bc4];
            }
            __syncthreads();

#pragma unroll
            for (int kk = 0; kk < 32; ++kk) {
                float4 a = *(const float4*)&As[kk][ty * 4];  // wave-uniform (bcast)
                float4 b = *(const float4*)&Bs[kk][tx * 4];
                acc[0][0] += a.x * b.x; acc[0][1] += a.x * b.y;
                acc[0][2] += a.x * b.z; acc[0][3] += a.x * b.w;
                acc[1][0] += a.y * b.x; acc[1][1] += a.y * b.y;
                acc[1][2] += a.y * b.z; acc[1][3] += a.y * b.w;
                acc[2][0] += a.z * b.x; acc[2][1] += a.z * b.y;
                acc[2][2] += a.z * b.z; acc[2][3] += a.z * b.w;
                acc[3][0] += a.w * b.x; acc[3][1] += a.w * b.y;
                acc[3][2] += a.w * b.z; acc[3][3] += a.w * b.w;
            }
            __syncthreads();
        }

        float4 bj = *(const float4*)&bias[tx * 4];
#pragma unroll
        for (int i = 0; i < 4; ++i) {
            float4 v;
            v.x = acc[i][0] + bj.x;
            v.y = acc[i][1] + bj.y;
            v.z = acc[i][2] + bj.z;
            v.w = acc[i][3] + bj.w;
            *(float4*)&out[(size_t)(m0 + ty * 4 + i) * HDIM + tx * 4] = v;
        }

        if (mode == 0) {
            __syncthreads();    // all stores program-ordered before signal (hb)
            if (tid == 0)
                __hip_atomic_fetch_add(&flags[r * NCH + ch], 1u,
                                       __ATOMIC_RELEASE, __HIP_MEMORY_SCOPE_AGENT);
        }
        return;
    }

    // ================= SCAN: fp16-packed register-resident W =================
    float* h = (float*)smem;                          // 256 floats
    float (*red)[256] = (float(*)[256])(smem + 1024); // [16][256] partials

    const int r   = (int)blockIdx.x;
    const int jq  = tid & 63;       // column quad
    const int g   = tid >> 6;       // k-group (0..15)
    const int j0  = jq << 2;

    // W tile: cols j0..j0+3 x k in [16g,16g+16), packed as fp16 k-pairs.
    // 32 VGPRs total; live set ~62 fits the default 64-reg budget.
    const float* wp = Wh + (size_t)(g * 16) * HDIM + j0;
    LDW2(0) LDW2(1) LDW2(2) LDW2(3) LDW2(4) LDW2(5) LDW2(6) LDW2(7)
    PIN8(wA); PIN8(wB); PIN8(wC); PIN8(wD);

    if (tid < 256) h[tid] = h0v[(size_t)r * HDIM + tid];

    float* outr = out + (size_t)r * TSTEPS * HDIM;
    __syncthreads();

    float c_next = 0.f;
    for (int ch = 0; ch < NCH; ++ch) {
        if (mode == 0) {
            if (tid == 0) {
                const unsigned int* f = &flags[r * NCH + ch];
                while (__hip_atomic_load(f, __ATOMIC_RELAXED,
                                         __HIP_MEMORY_SCOPE_AGENT) == 0u)
                    __builtin_amdgcn_s_sleep(8);
                (void)__hip_atomic_load(f, __ATOMIC_ACQUIRE,
                                        __HIP_MEMORY_SCOPE_AGENT);
            }
            __syncthreads();    // acquire happens-before everyone's c reads
        }
        if (g < 4) c_next = outr[(size_t)(ch * CH_STEPS) * HDIM + tid];

        for (int tt = 0; tt < CH_STEPS; ++tt) {
            const int t = ch * CH_STEPS + tt;
            float c = c_next;
            if (g < 4 && tt + 1 < CH_STEPS)     // stay inside gated chunk
                c_next = outr[(size_t)(t + 1) * HDIM + tid];

            const float4* hv = (const float4*)(h + (g << 4));
            float4 ha = hv[0], hb = hv[1], hc = hv[2], hd = hv[3];
            float h0 = ha.x, h1 = ha.y, h2 = ha.z, h3 = ha.w;
            float h4 = hb.x, h5 = hb.y, h6 = hb.z, h7 = hb.w;
            float h8 = hc.x, h9 = hc.y, h10 = hc.z, h11 = hc.w;
            float h12 = hd.x, h13 = hd.y, h14 = hd.z, h15 = hd.w;

            float a0 = 0.f, a1 = 0.f, a2 = 0.f, a3 = 0.f;
            FMAMIX16(a0, wA0,wA1,wA2,wA3,wA4,wA5,wA6,wA7);
            FMAMIX16(a1, wB0,wB1,wB2,wB3,wB4,wB5,wB6,wB7);
            FMAMIX16(a2, wC0,wC1,wC2,wC3,wC4,wC5,wC6,wC7);
            FMAMIX16(a3, wD0,wD1,wD2,wD3,wD4,wD5,wD6,wD7);

            float4 accv; accv.x = a0; accv.y = a1; accv.z = a2; accv.w = a3;
            *(float4*)&red[g][j0] = accv;
            __syncthreads();

            if (tid < 256) {
                float s0 = red[0][tid] + red[1][tid];
                float s1 = red[2][tid] + red[3][tid];
                float s2 = red[4][tid] + red[5][tid];
                float s3 = red[6][tid] + red[7][tid];
                float s4 = red[8][tid] + red[9][tid];
                float s5 = red[10][tid] + red[11][tid];
                float s6 = red[12][tid] + red[13][tid];
                float s7 = red[14][tid] + red[15][tid];
                float s  = (((s0 + s1) + (s2 + s3)) + ((s4 + s5) + (s6 + s7))) + c;
                float e  = __expf(2.f * s);
                float hn = 1.f - 2.f / (e + 1.f);
                outr[(size_t)t * HDIM + tid] = hn;
                h[tid] = hn;
            }
            __syncthreads();
        }
    }
}

extern "C" void kernel_launch(void* const* d_in, const int* in_sizes, int n_in,
                              void* d_out, int out_size, void* d_ws, size_t ws_size,
                              hipStream_t stream) {
    const float* x  = (const float*)d_in[0];   // (64,512,256)
    const float* h0 = (const float*)d_in[1];   // (64,256)
    const float* Wx = (const float*)d_in[2];   // (256,256)
    const float* Wh = (const float*)d_in[3];   // (256,256)
    const float* b  = (const float*)d_in[4];   // (256)
    float* out = (float*)d_out;                // (64,512,256)

    const size_t flag_bytes = (size_t)NBATCH * NCH * sizeof(unsigned int);
    if (d_ws != nullptr && ws_size >= flag_bytes) {
        unsigned int* flags = (unsigned int*)d_ws;
        hipMemsetAsync(d_ws, 0, flag_bytes, stream);
        fused<<<SCAN_BLOCKS + GEMM_BLOCKS, 1024, 0, stream>>>(
            x, h0, Wx, Wh, b, out, flags, 0);
    } else {
        // Fallback: serialized two-pass.
        fused<<<SCAN_BLOCKS + GEMM_BLOCKS, 1024, 0, stream>>>(
            x, h0, Wx, Wh, b, out, nullptr, 1);
        fused<<<SCAN_BLOCKS, 1024, 0, stream>>>(
            x, h0, Wx, Wh, b, out, nullptr, 2);
    }
}